// Round 10
// baseline (29.165 us; speedup 1.0000x reference)
//
#include <hip/hip_runtime.h>
#include <hip/hip_bf16.h>

#define C_ 10
#define B_ 8192
#define F_ 256
#define O_ 64
#define DK_ 5
#define NBLK1 256   // k1 blocks -> partial count
#define NG2   16    // second-level partial count

typedef __attribute__((ext_vector_type(8))) short short8;
typedef __attribute__((ext_vector_type(4))) float floatx4;

static __device__ __forceinline__ unsigned short f2bf(float f) {
    union { float f; unsigned u; } v; v.f = f;
    unsigned r = v.u + 0x7fffu + ((v.u >> 16) & 1u);  // round-nearest-even
    return (unsigned short)(r >> 16);
}

// ---------------- K1: per-block partial G only ------------------------------
// G_part[blk][c][f] = sum_{b in block} x[b,f]*y[b,c]   (no atomics, no memset)
__global__ __launch_bounds__(256) void k1_reduce(const float* __restrict__ x,
                                                 const float* __restrict__ y,
                                                 float* __restrict__ G_part) {
    __shared__ float xl[32 * F_];      // 32 KiB
    __shared__ float yl[32 * C_];
    const int b0 = blockIdx.x * 32;
    const int t  = threadIdx.x;

    for (int i = t; i < 32 * C_; i += 256) yl[i] = y[b0 * C_ + i];

    const int r  = t >> 6;             // row sub-slot 0..3
    const int f4 = (t & 63) * 4;       // 4 features per thread
#pragma unroll
    for (int j = 0; j < 8; ++j) {
        int row = r + 4 * j;           // 0..31
        float4 v = *(const float4*)(x + (size_t)(b0 + row) * F_ + f4);
        *(float4*)(xl + row * F_ + f4) = v;
    }
    __syncthreads();

    float acc[C_];
#pragma unroll
    for (int c = 0; c < C_; ++c) acc[c] = 0.f;

#pragma unroll 8
    for (int b = 0; b < 32; ++b) {
        float xv = xl[b * F_ + t];     // 2-way bank alias (free)
#pragma unroll
        for (int c = 0; c < C_; ++c) acc[c] = fmaf(yl[b * C_ + c], xv, acc[c]);
    }

    float* gp = G_part + (size_t)blockIdx.x * C_ * F_ + t;
#pragma unroll
    for (int c = 0; c < C_; ++c) gp[c * F_] = acc[c];   // coalesced, non-atomic
}

// ---------------- K1b: G2 fan-in + static weight->bf16 swizzled convert -----
// G2[g][c][f] = sum_{i<16} G_part[g*16+i][c][f];  grid = C_*NG2 = 160 blocks.
// Block (c,g) also converts weight[c][f][o] for f in [g*16,g*16+16) into
// WTB[c] swizzle-baked bf16 [o][k=f]: byte(o,f) = o*512 + ((2f) ^ ((o&7)<<4))
__global__ __launch_bounds__(256) void k1b_reduce(const float* __restrict__ G_part,
                                                  const float* __restrict__ weight,
                                                  float* __restrict__ G2,
                                                  unsigned short* __restrict__ WTB) {
    const int c = (int)blockIdx.x >> 4;
    const int g = (int)blockIdx.x & 15;
    const int t = threadIdx.x;

    const float* gp = G_part + (size_t)(g * 16) * C_ * F_ + c * F_ + t;
    float a0 = 0.f, a1 = 0.f, a2 = 0.f, a3 = 0.f;
#pragma unroll
    for (int i = 0; i < 16; i += 4) {   // 16 independent coalesced 1KB-row loads
        a0 += gp[(size_t)(i + 0) * C_ * F_];
        a1 += gp[(size_t)(i + 1) * C_ * F_];
        a2 += gp[(size_t)(i + 2) * C_ * F_];
        a3 += gp[(size_t)(i + 3) * C_ * F_];
    }
    G2[(size_t)g * C_ * F_ + c * F_ + t] = (a0 + a1) + (a2 + a3);

    // weight convert (unscaled, static per call): 1024 elems per block
    const int o  = t & 63;
    const int fq = t >> 6;              // 0..3
    const int f0 = g * 16 + fq * 4;
    const float* wsrc = weight + (size_t)c * F_ * O_;
    ushort4 v;
    v.x = f2bf(wsrc[(f0 + 0) * O_ + o]);   // lanes o -> coalesced 256B
    v.y = f2bf(wsrc[(f0 + 1) * O_ + o]);
    v.z = f2bf(wsrc[(f0 + 2) * O_ + o]);
    v.w = f2bf(wsrc[(f0 + 3) * O_ + o]);
    char* wb = (char*)(WTB + (size_t)c * O_ * F_);
    *(ushort4*)(wb + o * 512 + ((2 * f0) ^ ((o & 7) << 4))) = v;  // 8B aligned
}

// ---------------- K3: fused softmax + A-scaling + MFMA GEMM -----------------
// Per block (tile, c): prefetch x f32, stage WTB[c] (cheap, pre-swizzled),
// reduce G2 + softmax -> a2s[] in LDS, scale A in registers to bf16, MFMA.
__global__ __launch_bounds__(256) void k3_fused(const float* __restrict__ x,
                                                const float* __restrict__ G2,
                                                const float* __restrict__ w_key,
                                                const float* __restrict__ w_query,
                                                const float* __restrict__ w_value,
                                                const float* __restrict__ bias,
                                                const unsigned short* __restrict__ WTB,
                                                float* __restrict__ out) {
    __shared__ unsigned short wt[O_ * F_];  // 32 KiB swizzled [o][k]
    __shared__ float a2s[F_];
    __shared__ float wred[4];
    const int c  = blockIdx.y;
    const int b0 = blockIdx.x * 64;
    const int t  = threadIdx.x;
    const int w  = t >> 6;
    const int l  = t & 63;
    const int lr = l & 15;
    const int lg = l >> 4;

    // 1) x prefetch FIRST (f32): 8 k-slices x 32B, overlaps all prep below
    const float* xr = x + (size_t)(b0 + w * 16 + lr) * F_;
    float4 araw0[8], araw1[8];
#pragma unroll
    for (int k0 = 0; k0 < 8; ++k0) {
        araw0[k0] = *(const float4*)(xr + k0 * 32 + lg * 8);
        araw1[k0] = *(const float4*)(xr + k0 * 32 + lg * 8 + 4);
    }
    const float bo_r = bias[c * O_ + lr];        // for n=0; others below
    const float bo1  = bias[c * O_ + 16 + lr];
    const float bo2  = bias[c * O_ + 32 + lr];
    const float bo3  = bias[c * O_ + 48 + lr];

    // 2) stage WTB[c] linearly (swizzle pre-baked, L2/L3-hot)
    {
        const short8* src = (const short8*)(WTB + (size_t)c * O_ * F_);
        short8* dst = (short8*)wt;
#pragma unroll
        for (int j = 0; j < 8; ++j) dst[t + 256 * j] = src[t + 256 * j];
    }

    // 3) G2 reduce for (c, f=t) + softmax -> a2s[]
    {
        const float* gp = G2 + c * F_ + t;
        float g0 = 0.f, g1 = 0.f, g2 = 0.f, g3 = 0.f;
#pragma unroll
        for (int i = 0; i < NG2; i += 4) {
            g0 += gp[(size_t)(i + 0) * C_ * F_];
            g1 += gp[(size_t)(i + 1) * C_ * F_];
            g2 += gp[(size_t)(i + 2) * C_ * F_];
            g3 += gp[(size_t)(i + 3) * C_ * F_];
        }
        float g = (g0 + g1) + (g2 + g3);

        float s = 0.f;
#pragma unroll
        for (int k = 0; k < DK_; ++k) s += w_key[c * DK_ + k] * w_query[c * DK_ + k];

        float z = s * g * (1.0f / (float)B_);
        float m = z;
#pragma unroll
        for (int off = 32; off >= 1; off >>= 1) m = fmaxf(m, __shfl_xor(m, off));
        if ((t & 63) == 0) wred[t >> 6] = m;
        __syncthreads();
        float mm = fmaxf(fmaxf(wred[0], wred[1]), fmaxf(wred[2], wred[3]));
        a2s[t] = expf(z - mm) * w_value[c];
    }
    __syncthreads();   // wt staged + a2s ready

    // 4) scale A in registers: afr[k0] = bf16(x * a2)
    short8 afr[8];
#pragma unroll
    for (int k0 = 0; k0 < 8; ++k0) {
        const int kk = k0 * 32 + lg * 8;
        float4 s0 = *(const float4*)(a2s + kk);      // broadcast within lg group
        float4 s1 = *(const float4*)(a2s + kk + 4);
        short8 fr;
        fr[0] = (short)f2bf(araw0[k0].x * s0.x);
        fr[1] = (short)f2bf(araw0[k0].y * s0.y);
        fr[2] = (short)f2bf(araw0[k0].z * s0.z);
        fr[3] = (short)f2bf(araw0[k0].w * s0.w);
        fr[4] = (short)f2bf(araw1[k0].x * s1.x);
        fr[5] = (short)f2bf(araw1[k0].y * s1.y);
        fr[6] = (short)f2bf(araw1[k0].z * s1.z);
        fr[7] = (short)f2bf(araw1[k0].w * s1.w);
        afr[k0] = fr;
    }

    floatx4 acc[4];
    acc[0] = (floatx4){bo_r, bo_r, bo_r, bo_r};
    acc[1] = (floatx4){bo1, bo1, bo1, bo1};
    acc[2] = (floatx4){bo2, bo2, bo2, bo2};
    acc[3] = (floatx4){bo3, bo3, bo3, bo3};

#pragma unroll
    for (int k0 = 0; k0 < 8; ++k0) {
#pragma unroll
        for (int n = 0; n < 4; ++n) {
            int o = n * 16 + lr;
            int byte = o * 512 + ((k0 * 64 + lg * 16) ^ ((o & 7) << 4));
            short8 bf = *(const short8*)((const char*)wt + byte);  // conflict-free
            acc[n] = __builtin_amdgcn_mfma_f32_16x16x32_bf16(afr[k0], bf, acc[n], 0, 0, 0);
        }
    }

    // D layout: col = lane&15, row = (lane>>4)*4 + reg
#pragma unroll
    for (int n = 0; n < 4; ++n) {
        int col = n * 16 + lr;
#pragma unroll
        for (int r = 0; r < 4; ++r) {
            int row = b0 + w * 16 + lg * 4 + r;
            out[((size_t)c * B_ + row) * O_ + col] = acc[n][r];
        }
    }
}

extern "C" void kernel_launch(void* const* d_in, const int* in_sizes, int n_in,
                              void* d_out, int out_size, void* d_ws, size_t ws_size,
                              hipStream_t stream) {
    const float* x       = (const float*)d_in[0];
    const float* y       = (const float*)d_in[1];
    const float* w_key   = (const float*)d_in[2];
    const float* w_query = (const float*)d_in[3];
    const float* w_value = (const float*)d_in[4];
    const float* weight  = (const float*)d_in[5];
    const float* bias    = (const float*)d_in[6];
    float* out = (float*)d_out;

    char* ws = (char*)d_ws;
    float*          G_part = (float*)ws;                           // 2.62 MiB
    float*          G2     = G_part + (size_t)NBLK1 * C_ * F_;     // 160 KiB
    unsigned short* WTB    = (unsigned short*)(G2 + (size_t)NG2 * C_ * F_);  // 320 KiB

    k1_reduce<<<NBLK1, 256, 0, stream>>>(x, y, G_part);
    k1b_reduce<<<C_ * NG2, 256, 0, stream>>>(G_part, weight, G2, WTB);
    dim3 g3(B_ / 64, C_);
    k3_fused<<<g3, 256, 0, stream>>>(x, G2, w_key, w_query, w_value, bias, WTB, out);
}